// Round 7
// baseline (357.305 us; speedup 1.0000x reference)
//
#include <hip/hip_runtime.h>
#include <hip/hip_fp16.h>

// Fused 8-step diffusion: ONE 1024-thread block per (n,c) plane
// (256 blocks = exactly 1 per CU; 16 waves/CU by construction).
// No halo redundancy, no inter-block anything. Each thread owns 4 rows x 4
// cols; weights |.|-normalized once, held fp16: rows p=0..2 fully in regs
// (54 VGPRs), p=3 taps k=0..5 in regs (12), p=3 taps k=6..8 in 24KB LDS
// (insurance to stay under the HARD 128-VGPR cap of 1024-thread blocks —
// R3-R5 showed demand>cap means catastrophic scratch spill, not graceful).
// Row halos via 32KB LDS, column halos via wave shuffles + border zeroing.

constexpr int H = 128, W = 128, PLANE = H * W;
constexpr int NSTEP = 8;
constexpr int RPT = 4;            // rows per thread
constexpr int NRG = 32;           // row-groups (tid>>5)

// 6-wide column window (cols j0-1 .. j0+4) from a float4 row segment
#define MKWIN(D, V) do {                                                     \
    (D)[1] = (V).x; (D)[2] = (V).y; (D)[3] = (V).z; (D)[4] = (V).w;          \
    float _l = __shfl_up((V).w, 1);                                          \
    float _r = __shfl_down((V).x, 1);                                        \
    (D)[0] = (quad == 0)  ? 0.f : _l;                                        \
    (D)[5] = (quad == 31) ? 0.f : _r;                                        \
} while (0)

__global__ __launch_bounds__(1024)
void diff_fused(const float* __restrict__ xin,
                const float* __restrict__ wgt,
                float* __restrict__ out)
{
    __shared__ float ldsT[NRG][W];      // top row (r0)   per rg  (16 KB)
    __shared__ float ldsB[NRG][W];      // bottom (r0+3)  per rg  (16 KB)
    __shared__ uint2 wh3L[3][1024];     // p=3, k=6..8 weights    (24 KB)

    const int tid  = threadIdx.x;
    const int quad = tid & 31;          // cols 4q..4q+3
    const int rg   = tid >> 5;          // 0..31
    const int j0   = quad * 4;
    const int r0   = rg * RPT;          // rows r0..r0+3, all in-plane
    const size_t pbase = (size_t)blockIdx.x * PLANE;

    const float* __restrict__ xp = xin + pbase;
    const float* __restrict__ wb = wgt + pbase * 9;   // (n*576+c*9)*PLANE

    // ---- weights: load once, |.|-normalize fp32, pack fp16 ----
    __half2 whr[3][9][2];     // p=0..2           : 54 VGPRs
    __half2 wh3[6][2];        // p=3, k=0..5      : 12 VGPRs
    #pragma unroll
    for (int p = 0; p < RPT; ++p) {
        const float* wr = wb + (r0 + p) * W + j0;
        float a[9][4];
        float s0 = 0.f, s1 = 0.f, s2 = 0.f, s3 = 0.f;
        #pragma unroll
        for (int k = 0; k < 9; ++k) {
            float4 v = *reinterpret_cast<const float4*>(wr + (size_t)k * PLANE);
            a[k][0] = fabsf(v.x); a[k][1] = fabsf(v.y);
            a[k][2] = fabsf(v.z); a[k][3] = fabsf(v.w);
            s0 += a[k][0]; s1 += a[k][1]; s2 += a[k][2]; s3 += a[k][3];
        }
        s0 = 1.f / s0; s1 = 1.f / s1; s2 = 1.f / s2; s3 = 1.f / s3;
        #pragma unroll
        for (int k = 0; k < 9; ++k) {
            __half2 h0 = __halves2half2(__float2half_rn(a[k][0] * s0),
                                        __float2half_rn(a[k][1] * s1));
            __half2 h1 = __halves2half2(__float2half_rn(a[k][2] * s2),
                                        __float2half_rn(a[k][3] * s3));
            if (p < 3)        { whr[p][k][0] = h0; whr[p][k][1] = h1; }
            else if (k < 6)   { wh3[k][0] = h0;    wh3[k][1] = h1; }
            else {
                wh3L[k - 6][tid] =
                    make_uint2(__builtin_bit_cast(unsigned int, h0),
                               __builtin_bit_cast(unsigned int, h1));
            }
        }
    }

    // ---- x patch into registers (after weights: lower peak pressure) ----
    float4 xr[RPT];
    #pragma unroll
    for (int p = 0; p < RPT; ++p)
        xr[p] = *reinterpret_cast<const float4*>(xp + (r0 + p) * W + j0);

    // ---- 8 fused steps, zero global traffic ----
    #pragma unroll 1
    for (int s = 0; s < NSTEP; ++s) {
        *reinterpret_cast<float4*>(&ldsT[rg][j0]) = xr[0];
        *reinterpret_cast<float4*>(&ldsB[rg][j0]) = xr[RPT - 1];
        __syncthreads();   // also covers wh3L visibility on s==0
        float4 up = make_float4(0.f, 0.f, 0.f, 0.f);   // row r0-1
        float4 dn = make_float4(0.f, 0.f, 0.f, 0.f);   // row r0+4
        if (rg > 0)       up = *reinterpret_cast<const float4*>(&ldsB[rg - 1][j0]);
        if (rg < NRG - 1) dn = *reinterpret_cast<const float4*>(&ldsT[rg + 1][j0]);
        __syncthreads();   // reads done before next step's writes

        float win[3][6];
        MKWIN(win[0], up);       // input row r0-1
        MKWIN(win[1], xr[0]);    // input row r0
        #pragma unroll
        for (int p = 0; p < RPT; ++p) {
            if (p < RPT - 1) { MKWIN(win[(p + 2) % 3], xr[p + 1]); }
            else             { MKWIN(win[(p + 2) % 3], dn); }
            float a0 = 0.f, a1 = 0.f, a2 = 0.f, a3 = 0.f;
            #pragma unroll
            for (int di = 0; di < 3; ++di) {
                #pragma unroll
                for (int dj = 0; dj < 3; ++dj) {
                    const int k = di * 3 + dj;
                    __half2 w0, w1;
                    if (p < 3)      { w0 = whr[p][k][0]; w1 = whr[p][k][1]; }
                    else if (k < 6) { w0 = wh3[k][0];    w1 = wh3[k][1]; }
                    else {
                        uint2 lv = wh3L[k - 6][tid];
                        w0 = __builtin_bit_cast(__half2, lv.x);
                        w1 = __builtin_bit_cast(__half2, lv.y);
                    }
                    a0 = fmaf(__low2float (w0), win[(p + di) % 3][dj + 0], a0);
                    a1 = fmaf(__high2float(w0), win[(p + di) % 3][dj + 1], a1);
                    a2 = fmaf(__low2float (w1), win[(p + di) % 3][dj + 2], a2);
                    a3 = fmaf(__high2float(w1), win[(p + di) % 3][dj + 3], a3);
                }
            }
            xr[p] = make_float4(a0, a1, a2, a3);   // old xr[p] fully consumed
        }
    }

    // ---- store (coalesced float4) ----
    float* __restrict__ op = out + pbase;
    #pragma unroll
    for (int p = 0; p < RPT; ++p)
        *reinterpret_cast<float4*>(op + (r0 + p) * W + j0) = xr[p];
}

extern "C" void kernel_launch(void* const* d_in, const int* in_sizes, int n_in,
                              void* d_out, int out_size, void* d_ws, size_t ws_size,
                              hipStream_t stream)
{
    const float* x = (const float*)d_in[0];
    const float* w = (const float*)d_in[1];
    float* out = (float*)d_out;
    (void)d_ws; (void)ws_size; (void)in_sizes; (void)n_in; (void)out_size;

    // 256 blocks (one per plane) x 1024 threads = exactly 1 block per CU
    diff_fused<<<dim3(4 * 64), dim3(1024), 0, stream>>>(x, w, out);
}